// Round 11
// baseline (1622.579 us; speedup 1.0000x reference)
//
#include <hip/hip_runtime.h>
#include <math.h>

namespace {

constexpr float ALPHA = 0.3f;
constexpr int B  = 16;
constexpr int N  = 1024;
constexpr int H  = 256;
constexpr int H2 = 512;
constexpr int NT = B * N;        // 16384 total nodes
constexpr int NE = N - 1;        // 1023 MST edges per batch
constexpr int CAP = 32;          // adjacency capacity per node (MST degree << 32)

__device__ __forceinline__ unsigned umin32(unsigned a, unsigned b) { return a < b ? a : b; }

// ---------------- row squared-norms: n2[row] = sum_k x[row][k]^2 ----------------
__global__ void n2_kernel(const float* __restrict__ x, float* __restrict__ n2) {
  int wave = threadIdx.x >> 6, lane = threadIdx.x & 63;
  int row  = blockIdx.x * 4 + wave;
  float4 v = *(const float4*)(x + (size_t)row * H + lane * 4);
  float s  = v.x * v.x + v.y * v.y + v.z * v.z + v.w * v.w;
  #pragma unroll
  for (int off = 32; off; off >>= 1) s += __shfl_xor(s, off);
  if (lane == 0) n2[row] = s;
}

// ---------------- distance matrix: 128x128 tile, 8x8 per thread -----------------
__global__ __launch_bounds__(256) void dist_kernel(const float* __restrict__ x,
    const float* __restrict__ n2, float* __restrict__ dist) {
  __shared__ float As[16][132], Bs[16][132];
  const int bb = blockIdx.z;
  const int i0 = blockIdx.y * 128, j0 = blockIdx.x * 128;
  const int t = threadIdx.x, tx = t & 15, ty = t >> 4;
  const float* xb = x + (size_t)bb * N * H;
  float acc[8][8] = {};
  for (int kc = 0; kc < H; kc += 16) {
    #pragma unroll
    for (int u = 0; u < 2; ++u) {
      int q = t + u * 256;
      int row = q >> 2, kf = (q & 3) * 4;          // 128 rows x 4 float4 of k
      float4 a = *(const float4*)(xb + (size_t)(i0 + row) * H + kc + kf);
      As[kf + 0][row] = a.x; As[kf + 1][row] = a.y;
      As[kf + 2][row] = a.z; As[kf + 3][row] = a.w;
      float4 bv = *(const float4*)(xb + (size_t)(j0 + row) * H + kc + kf);
      Bs[kf + 0][row] = bv.x; Bs[kf + 1][row] = bv.y;
      Bs[kf + 2][row] = bv.z; Bs[kf + 3][row] = bv.w;
    }
    __syncthreads();
    #pragma unroll
    for (int kk = 0; kk < 16; ++kk) {
      float4 a0 = *(const float4*)&As[kk][ty * 4];
      float4 a1 = *(const float4*)&As[kk][64 + ty * 4];
      float4 b0 = *(const float4*)&Bs[kk][tx * 4];
      float4 b1 = *(const float4*)&Bs[kk][64 + tx * 4];
      float ar[8] = {a0.x,a0.y,a0.z,a0.w,a1.x,a1.y,a1.z,a1.w};
      float br[8] = {b0.x,b0.y,b0.z,b0.w,b1.x,b1.y,b1.z,b1.w};
      #pragma unroll
      for (int r = 0; r < 8; ++r)
        #pragma unroll
        for (int c = 0; c < 8; ++c) acc[r][c] += ar[r] * br[c];
    }
    __syncthreads();
  }
  float n2i[8], n2j[8];
  #pragma unroll
  for (int r = 0; r < 8; ++r)
    n2i[r] = n2[bb * N + i0 + (r < 4 ? ty * 4 + r : 64 + ty * 4 + r - 4)];
  #pragma unroll
  for (int c = 0; c < 8; ++c)
    n2j[c] = n2[bb * N + j0 + (c < 4 ? tx * 4 + c : 64 + tx * 4 + c - 4)];
  #pragma unroll
  for (int r = 0; r < 8; ++r) {
    int mi = i0 + (r < 4 ? ty * 4 + r : 64 + ty * 4 + r - 4);
    float o[8];
    #pragma unroll
    for (int c = 0; c < 8; ++c) {
      float d2 = (n2i[r] + n2j[c]) - 2.0f * acc[r][c];
      o[c] = sqrtf(fmaxf(d2, 0.0f));
    }
    float* dst = dist + ((size_t)bb * N + mi) * N + j0;
    *(float4*)(dst + tx * 4)      = make_float4(o[0], o[1], o[2], o[3]);
    *(float4*)(dst + 64 + tx * 4) = make_float4(o[4], o[5], o[6], o[7]);
  }
}

// ---------------- Prim MST: 4 waves/batch + runner-up L2 touch-prefetch ----------
// Node j: thread j>>2, slot j&3; all-scalar per-thread state (R8, proven).
// Each iter: ONE top-2 block selection (winner exact; runner-up = predicted next
// winner). Real load (asm) of winner's row is consumed next iter via hand
// s_waitcnt vmcnt(1); a TOUCH load (asm) of the runner-up row warms L2 one
// period early. Touch dests get FAKE USES (asm, component-wise scalars -- clang
// rejects aggregate asm inputs) placed exactly where each def has retired,
// pinning liveness across the in-flight window so the allocator can never
// reuse those VGPRs while a load targets them (the R9 crash).
__device__ __forceinline__ unsigned wave_min_u32(unsigned x) {
  unsigned t;
  t = (unsigned)__builtin_amdgcn_update_dpp((int)x, (int)x, 0x111, 0xf, 0xf, false); x = umin32(x, t);
  t = (unsigned)__builtin_amdgcn_update_dpp((int)x, (int)x, 0x112, 0xf, 0xf, false); x = umin32(x, t);
  t = (unsigned)__builtin_amdgcn_update_dpp((int)x, (int)x, 0x114, 0xf, 0xf, false); x = umin32(x, t);
  t = (unsigned)__builtin_amdgcn_update_dpp((int)x, (int)x, 0x118, 0xf, 0xf, false); x = umin32(x, t);
  x = umin32(x, (unsigned)__shfl_xor((int)x, 16));
  x = umin32(x, (unsigned)__shfl_xor((int)x, 32));
  return (unsigned)__builtin_amdgcn_readlane((int)x, 63);
}

struct Sel3 { unsigned w; int j; int j2; };

// Block-wide top-2 argmin. u64 keys (w<<32|node): u64-min == lowest-index
// tie-break == jnp.argmin. Parity-buffered smin: one barrier per call; the
// barrier of the NEXT call (other parity) separates this call's reads from
// the next rewrite of the same slot.
__device__ __forceinline__ Sel3 block_select2(unsigned mw0, unsigned mw1,
    unsigned mw2, unsigned mw3, int tid, int wid, int lane,
    unsigned long long (*s1)[4], unsigned long long (*s2)[4], int pb) {
  unsigned lm = umin32(umin32(mw0, mw1), umin32(mw2, mw3));
  unsigned wm = wave_min_u32(lm);
  unsigned mb = (mw0 == wm ? 1u : 0u) | (mw1 == wm ? 2u : 0u) |
                (mw2 == wm ? 4u : 0u) | (mw3 == wm ? 8u : 0u);
  unsigned long long bal = __ballot(mb != 0);
  int fl = __ffsll(bal) - 1;
  int slot = __ffs((unsigned)__builtin_amdgcn_readlane((int)mb, fl)) - 1;
  int wj = (wid << 8) | (fl << 2) | slot;            // wave winner node id
  // wave second (exclude winner slot, owner thread only)
  unsigned e0 = mw0, e1 = mw1, e2 = mw2, e3 = mw3;
  if (tid == (wj >> 2)) {
    int sl = wj & 3;
    if (sl == 0) e0 = ~0u; else if (sl == 1) e1 = ~0u;
    else if (sl == 2) e2 = ~0u; else e3 = ~0u;
  }
  unsigned lm2 = umin32(umin32(e0, e1), umin32(e2, e3));
  unsigned wm2 = wave_min_u32(lm2);
  unsigned mb2 = (e0 == wm2 ? 1u : 0u) | (e1 == wm2 ? 2u : 0u) |
                 (e2 == wm2 ? 4u : 0u) | (e3 == wm2 ? 8u : 0u);
  unsigned long long bal2 = __ballot(mb2 != 0);
  int fl2 = __ffsll(bal2) - 1;
  int slot2 = __ffs((unsigned)__builtin_amdgcn_readlane((int)mb2, fl2)) - 1;
  int wj2 = (wid << 8) | (fl2 << 2) | slot2;
  if (lane == 0) {
    s1[pb][wid] = ((unsigned long long)wm  << 32) | (unsigned)wj;
    s2[pb][wid] = ((unsigned long long)wm2 << 32) | (unsigned)wj2;
  }
  __syncthreads();
  unsigned long long a0 = s1[pb][0], a1 = s1[pb][1], a2 = s1[pb][2], a3 = s1[pb][3];
  unsigned long long b0 = s2[pb][0], b1 = s2[pb][1], b2 = s2[pb][2], b3 = s2[pb][3];
  unsigned long long w01 = a0 < a1 ? a0 : a1, w23 = a2 < a3 ? a2 : a3;
  unsigned long long win = w01 < w23 ? w01 : w23;
  unsigned long long c0 = (a0 == win) ? b0 : a0;
  unsigned long long c1 = (a1 == win) ? b1 : a1;
  unsigned long long c2 = (a2 == win) ? b2 : a2;
  unsigned long long c3 = (a3 == win) ? b3 : a3;
  unsigned long long r01 = c0 < c1 ? c0 : c1, r23 = c2 < c3 ? c2 : c3;
  unsigned long long run = r01 < r23 ? r01 : r23;
  Sel3 r;
  r.w  = (unsigned)(win >> 32);
  r.j  = (int)(unsigned)(win & 0x3FFu);
  r.j2 = (int)(unsigned)(run & 0x3FFu);
  return r;
}

// 16B row-chunk load, invisible to the compiler's waitcnt pass. Early-clobber
// so the dest can never alias the address pair.
__device__ __forceinline__ void load16(const float* p, float4& x) {
  asm volatile("global_load_dwordx4 %0, %1, off" : "=&v"(x) : "v"(p) : "memory");
}

// Component-wise liveness pin (clang rejects float4 asm inputs).
#define PIN4(V) asm volatile("" :: "v"((V).x), "v"((V).y), "v"((V).z), "v"((V).w))

// One Prim step. DEAD = touch sink for this parity; its def from 2 iters ago
// retired at this iter's vmcnt(1), so the fake use here pins its liveness over
// the whole in-flight window without waiting on anything.
#define PRIM_ITER(kk, PB, DEAD)                                                   \
  {                                                                               \
    asm volatile("s_waitcnt vmcnt(1)" ::: "memory");  /* real row arrived */      \
    __builtin_amdgcn_sched_barrier(0);                /* rule #18 fence */        \
    PIN4(DEAD);                                       /* liveness pin (retired) */\
    unsigned r0 = __float_as_uint(xq.x), r1 = __float_as_uint(xq.y);              \
    unsigned r2 = __float_as_uint(xq.z), r3 = __float_as_uint(xq.w);              \
    unsigned q0 = r0 | rm0, q1 = r1 | rm1, q2 = r2 | rm2, q3 = r3 | rm3;          \
    mw0 = umin32(mw0, q0); mw1 = umin32(mw1, q1);                                 \
    mw2 = umin32(mw2, q2); mw3 = umin32(mw3, q3);                                 \
    Sel3 se = block_select2(mw0, mw1, mw2, mw3, tid, wid, lane, s1, s2, PB);      \
    const int nj = se.j;                                                          \
    load16(Db + (size_t)nj * N + jbase, xq);          /* real: next winner */     \
    load16(Db + (size_t)se.j2 * N + jbase, DEAD);     /* touch: runner-up */      \
    if (r0 < d0) { pa0 = cj; d0 = r0; }               /* strict <, matches ref */ \
    if (r1 < d1) { pa1 = cj; d1 = r1; }                                           \
    if (r2 < d2) { pa2 = cj; d2 = r2; }                                           \
    if (r3 < d3) { pa3 = cj; d3 = r3; }                                           \
    if ((nj >> 2) == tid) {                           /* owner: emit + mask */    \
      int sl = nj & 3;                                                            \
      int pv = pa0; if (sl == 1) pv = pa1; if (sl == 2) pv = pa2;                 \
      if (sl == 3) pv = pa3;                                                      \
      epv[kk] = pv; evv[kk] = nj; ews[kk] = __uint_as_float(se.w);                \
      if (sl == 0) { rm0 = ~0u; mw0 = ~0u; }                                      \
      if (sl == 1) { rm1 = ~0u; mw1 = ~0u; }                                      \
      if (sl == 2) { rm2 = ~0u; mw2 = ~0u; }                                      \
      if (sl == 3) { rm3 = ~0u; mw3 = ~0u; }                                      \
    }                                                                             \
    cj = nj;                                                                      \
  }

__global__ __launch_bounds__(256, 1) void prim_kernel(const float* __restrict__ dist,
    int* __restrict__ ep, int* __restrict__ ev, float* __restrict__ ewt) {
  __shared__ unsigned long long s1[2][4], s2[2][4];
  __shared__ int epv[NE];
  __shared__ int evv[NE];
  __shared__ float ews[NE];
  const int b = blockIdx.x;
  const int tid = threadIdx.x, wid = tid >> 6, lane = tid & 63;
  const float* Db = dist + (size_t)b * N * N;
  const int jbase = tid * 4;                          // this thread's 4 nodes

  unsigned d0, d1, d2, d3;                            // mind (scalars)
  {
    float4 v = *(const float4*)(Db + jbase);          // row 0 (plain, pre-loop)
    d0 = __float_as_uint(v.x); d1 = __float_as_uint(v.y);
    d2 = __float_as_uint(v.z); d3 = __float_as_uint(v.w);
  }
  unsigned mw0 = d0, mw1 = d1, mw2 = d2, mw3 = d3;
  unsigned rm0 = 0, rm1 = 0, rm2 = 0, rm3 = 0;
  int pa0 = 0, pa1 = 0, pa2 = 0, pa3 = 0;
  if (tid == 0) { rm0 = ~0u; mw0 = ~0u; }             // node 0 in tree

  // ---- edge 0: select (pb=0), emit, issue real + touch ----
  Sel3 s0 = block_select2(mw0, mw1, mw2, mw3, tid, wid, lane, s1, s2, 0);
  int cj = s0.j;
  if ((cj >> 2) == tid) {
    int sl = cj & 3;
    int pv = pa0; if (sl == 1) pv = pa1; if (sl == 2) pv = pa2; if (sl == 3) pv = pa3;
    epv[0] = pv; evv[0] = cj; ews[0] = __uint_as_float(s0.w);
    if (sl == 0) { rm0 = ~0u; mw0 = ~0u; }
    if (sl == 1) { rm1 = ~0u; mw1 = ~0u; }
    if (sl == 2) { rm2 = ~0u; mw2 = ~0u; }
    if (sl == 3) { rm3 = ~0u; mw3 = ~0u; }
  }
  float4 xq;
  float4 deadA = make_float4(0.f, 0.f, 0.f, 0.f);
  float4 deadB = make_float4(0.f, 0.f, 0.f, 0.f);
  load16(Db + (size_t)cj * N + jbase, xq);            // outstanding: [real]
  load16(Db + (size_t)s0.j2 * N + jbase, deadB);      // outstanding: [real, touch]

  for (int k = 1; k + 1 < NE; k += 2) {               // 511 pairs = iters 1..1022
    PRIM_ITER(k,     1, deadA);
    PRIM_ITER(k + 1, 0, deadB);
  }

  asm volatile("s_waitcnt vmcnt(0)" ::: "memory");    // drain dangling loads
  PIN4(deadA); PIN4(deadB); PIN4(xq);                 // pin final defs
  __syncthreads();                                    // epv/evv/ews visible
  for (int e = tid; e < NE; e += 256) {
    ep[b * NE + e]  = epv[e];
    ev[b * NE + e]  = evv[e];
    ewt[b * NE + e] = ews[e];
  }
}

// ---------------- adjacency + deg^-1/2 (deterministic, no atomics) --------------
__global__ void adj_kernel(const int* __restrict__ ep, const int* __restrict__ ev,
    const float* __restrict__ ewt, int* __restrict__ adjI, float* __restrict__ adjW,
    int* __restrict__ cnt, float* __restrict__ dinv) {
  int i = blockIdx.x * 256 + threadIdx.x;
  int b = i >> 10, loc = i & 1023;
  const int* epb = ep + b * NE;
  const int* evb = ev + b * NE;
  const float* ewb = ewt + b * NE;
  int c = 0; float wsum = 0.0f;
  for (int k = 0; k < NE; ++k) {
    int p = epb[k], v = evb[k];
    if (p == loc || v == loc) {
      float w = ewb[k];
      wsum += w;
      int nb = (p == loc) ? v : p;
      if (c < CAP) { adjI[i * CAP + c] = (b << 10) + nb; adjW[i * CAP + c] = w; }
      ++c;
    }
  }
  cnt[i]  = c < CAP ? c : CAP;
  dinv[i] = 1.0f / sqrtf(wsum + 1.0f);
}

// ---------------- SSG propagation: h = alpha*x + (1-alpha)*A_hat x --------------
template <int HH>
__global__ void prop_kernel(const float* __restrict__ x, const int* __restrict__ adjI,
    const float* __restrict__ adjW, const int* __restrict__ cnt,
    const float* __restrict__ dinv, float* __restrict__ h) {
  constexpr int U = HH / 256;
  int wave = threadIdx.x >> 6, lane = threadIdx.x & 63;
  int i = blockIdx.x * 4 + wave;
  float dv = dinv[i];
  int c = cnt[i];
  float selfc = ALPHA + (1.0f - ALPHA) * dv * dv;
  float4 acc[U];
  const float* xi = x + (size_t)i * HH + lane * 4;
  #pragma unroll
  for (int u = 0; u < U; ++u) {
    float4 v = *(const float4*)(xi + u * 256);
    acc[u].x = selfc * v.x; acc[u].y = selfc * v.y;
    acc[u].z = selfc * v.z; acc[u].w = selfc * v.w;
  }
  for (int e = 0; e < c; ++e) {
    int j   = adjI[i * CAP + e];
    float w = adjW[i * CAP + e];
    float coef = (1.0f - ALPHA) * dv * (w * dinv[j]);
    const float* xj = x + (size_t)j * HH + lane * 4;
    #pragma unroll
    for (int u = 0; u < U; ++u) {
      float4 v = *(const float4*)(xj + u * 256);
      acc[u].x += coef * v.x; acc[u].y += coef * v.y;
      acc[u].z += coef * v.z; acc[u].w += coef * v.w;
    }
  }
  float* ho = h + (size_t)i * HH + lane * 4;
  #pragma unroll
  for (int u = 0; u < U; ++u) *(float4*)(ho + u * 256) = acc[u];
}

// ---------------- fused GEMM + bias + tanh: 128x128 tile, 8x8 per thread --------
template <int K>
__global__ __launch_bounds__(256) void gemm_tanh_kernel(const float* __restrict__ A,
    const float* __restrict__ W, const float* __restrict__ bias, float* __restrict__ C) {
  __shared__ float As[16][132], Bs[16][132];
  const int m0 = blockIdx.x * 128, n0 = blockIdx.y * 128;
  const int t = threadIdx.x, tx = t & 15, ty = t >> 4;
  float acc[8][8] = {};
  for (int kc = 0; kc < K; kc += 16) {
    #pragma unroll
    for (int u = 0; u < 2; ++u) {
      int q = t + u * 256;
      int row = q >> 2, kf = (q & 3) * 4;
      float4 a = *(const float4*)(A + (size_t)(m0 + row) * K + kc + kf);
      As[kf + 0][row] = a.x; As[kf + 1][row] = a.y;
      As[kf + 2][row] = a.z; As[kf + 3][row] = a.w;
      int rowB = q >> 5, cf = (q & 31) * 4;
      *(float4*)&Bs[rowB][cf] = *(const float4*)(W + (size_t)(kc + rowB) * H2 + n0 + cf);
    }
    __syncthreads();
    #pragma unroll
    for (int kk = 0; kk < 16; ++kk) {
      float4 a0 = *(const float4*)&As[kk][ty * 4];
      float4 a1 = *(const float4*)&As[kk][64 + ty * 4];
      float4 b0 = *(const float4*)&Bs[kk][tx * 4];
      float4 b1 = *(const float4*)&Bs[kk][64 + tx * 4];
      float ar[8] = {a0.x,a0.y,a0.z,a0.w,a1.x,a1.y,a1.z,a1.w};
      float br[8] = {b0.x,b0.y,b0.z,b0.w,b1.x,b1.y,b1.z,b1.w};
      #pragma unroll
      for (int r = 0; r < 8; ++r)
        #pragma unroll
        for (int c = 0; c < 8; ++c) acc[r][c] += ar[r] * br[c];
    }
    __syncthreads();
  }
  float4 bi0 = *(const float4*)(bias + n0 + tx * 4);
  float4 bi1 = *(const float4*)(bias + n0 + 64 + tx * 4);
  float bb[8] = {bi0.x,bi0.y,bi0.z,bi0.w,bi1.x,bi1.y,bi1.z,bi1.w};
  #pragma unroll
  for (int r = 0; r < 8; ++r) {
    int m = m0 + (r < 4 ? ty * 4 + r : 64 + ty * 4 + r - 4);
    float o[8];
    #pragma unroll
    for (int c = 0; c < 8; ++c) o[c] = tanhf(acc[r][c] + bb[c]);
    float* dst = C + (size_t)m * H2 + n0;
    *(float4*)(dst + tx * 4)      = make_float4(o[0], o[1], o[2], o[3]);
    *(float4*)(dst + 64 + tx * 4) = make_float4(o[4], o[5], o[6], o[7]);
  }
}

// ---------------- mean pool over N nodes per graph ------------------------------
__global__ void pool_kernel(const float* __restrict__ x, float* __restrict__ pooled) {
  int b = blockIdx.x;
  int c = blockIdx.y * 256 + threadIdx.x;
  const float* xb = x + ((size_t)b << 10) * H2 + c;
  float s = 0.0f;
  for (int i = 0; i < N; ++i) s += xb[(size_t)i * H2];
  pooled[b * H2 + c] = s * (1.0f / N);
}

// ---------------- dense head: tanh(pooled@Wd+bd) @ Wo + bo ----------------------
__global__ void head_kernel(const float* __restrict__ pooled, const float* __restrict__ Wd,
    const float* __restrict__ bd, const float* __restrict__ Wo, const float* __restrict__ bo,
    float* __restrict__ out) {
  __shared__ float sp[512], sh[256];
  int b = blockIdx.x, t = threadIdx.x;
  sp[t] = pooled[b * H2 + t];
  sp[t + 256] = pooled[b * H2 + t + 256];
  __syncthreads();
  float acc = bd[t];
  for (int c2 = 0; c2 < 512; ++c2) acc += sp[c2] * Wd[c2 * 256 + t];
  sh[t] = tanhf(acc);
  __syncthreads();
  if (t < 8) {
    float o = bo[t];
    for (int j = 0; j < 256; ++j) o += sh[j] * Wo[j * 8 + t];
    out[b * 8 + t] = o;
  }
}

}  // namespace

extern "C" void kernel_launch(void* const* d_in, const int* in_sizes, int n_in,
                              void* d_out, int out_size, void* d_ws, size_t ws_size,
                              hipStream_t stream) {
  const float* feat = (const float*)d_in[0];
  const float* W1 = (const float*)d_in[1];
  const float* b1 = (const float*)d_in[2];
  const float* W2 = (const float*)d_in[3];
  const float* b2 = (const float*)d_in[4];
  const float* W3 = (const float*)d_in[5];
  const float* b3 = (const float*)d_in[6];
  const float* Wd = (const float*)d_in[7];
  const float* bd = (const float*)d_in[8];
  const float* Wo = (const float*)d_in[9];
  const float* bo = (const float*)d_in[10];
  float* out = (float*)d_out;
  char* ws = (char*)d_ws;

  float* dist = (float*)(ws);
  float* xcur = (float*)(ws);                        // reuses dist after prim
  float* hbuf = (float*)(ws + ((size_t)64 << 20));
  char* misc  = ws + ((size_t)96 << 20);
  int*   ep     = (int*)(misc);
  int*   ev     = (int*)(misc + 65536);
  float* ewt    = (float*)(misc + 131072);
  int*   cnt    = (int*)(misc + 196608);
  float* dinv   = (float*)(misc + 262144);
  int*   adjI   = (int*)(misc + 327680);
  float* adjW   = (float*)(misc + 327680 + 2097152);
  float* n2     = (float*)(misc + 327680 + 2 * 2097152);
  float* pooled = (float*)(misc + 327680 + 2 * 2097152 + 65536);

  n2_kernel<<<NT / 4, 256, 0, stream>>>(feat, n2);
  dist_kernel<<<dim3(8, 8, 16), 256, 0, stream>>>(feat, n2, dist);
  prim_kernel<<<B, 256, 0, stream>>>(dist, ep, ev, ewt);
  adj_kernel<<<NT / 256, 256, 0, stream>>>(ep, ev, ewt, adjI, adjW, cnt, dinv);

  prop_kernel<256><<<NT / 4, 256, 0, stream>>>(feat, adjI, adjW, cnt, dinv, hbuf);
  gemm_tanh_kernel<256><<<dim3(NT / 128, 4), 256, 0, stream>>>(hbuf, W1, b1, xcur);
  prop_kernel<512><<<NT / 4, 256, 0, stream>>>(xcur, adjI, adjW, cnt, dinv, hbuf);
  gemm_tanh_kernel<512><<<dim3(NT / 128, 4), 256, 0, stream>>>(hbuf, W2, b2, xcur);
  prop_kernel<512><<<NT / 4, 256, 0, stream>>>(xcur, adjI, adjW, cnt, dinv, hbuf);
  gemm_tanh_kernel<512><<<dim3(NT / 128, 4), 256, 0, stream>>>(hbuf, W3, b3, xcur);

  pool_kernel<<<dim3(B, H2 / 256), 256, 0, stream>>>(xcur, pooled);
  head_kernel<<<B, 256, 0, stream>>>(pooled, Wd, bd, Wo, bo, out);
}